// Round 2
// baseline (68.360 us; speedup 1.0000x reference)
//
#include <hip/hip_runtime.h>
#include <hip/hip_bf16.h>

typedef __bf16 bf16x8 __attribute__((ext_vector_type(8)));
typedef float  f32x4  __attribute__((ext_vector_type(4)));

#define MFMA16(a,b,c) __builtin_amdgcn_mfma_f32_16x16x32_bf16((a),(b),(c),0,0,0)

constexpr int Bn = 8192, Dd = 64, MT = 16;

__device__ __forceinline__ unsigned short f2bf(float f) {
    unsigned int u = __builtin_bit_cast(unsigned int, f);
    u = (u + 0x7FFFu + ((u >> 16) & 1u)) >> 16;   // RNE
    return (unsigned short)u;
}

__device__ __forceinline__ bf16x8 pack8(float4 a, float4 b) {
    union { bf16x8 v; unsigned short u[8]; } r;
    r.u[0] = f2bf(a.x); r.u[1] = f2bf(a.y); r.u[2] = f2bf(a.z); r.u[3] = f2bf(a.w);
    r.u[4] = f2bf(b.x); r.u[5] = f2bf(b.y); r.u[6] = f2bf(b.z); r.u[7] = f2bf(b.w);
    return r.v;
}

__device__ __forceinline__ bf16x8 pack8s(float v0, float v1, float v2, float v3,
                                         float v4, float v5, float v6, float v7) {
    union { bf16x8 v; unsigned short u[8]; } r;
    r.u[0] = f2bf(v0); r.u[1] = f2bf(v1); r.u[2] = f2bf(v2); r.u[3] = f2bf(v3);
    r.u[4] = f2bf(v4); r.u[5] = f2bf(v5); r.u[6] = f2bf(v6); r.u[7] = f2bf(v7);
    return r.v;
}

// Single fused kernel: no prep pass, no workspace. All weights are consumed
// as per-fragment loads from the raw fp32 inputs (W1 = 32 KB, Wf = 16 KB ->
// L1/L2-resident after first touch). W1^T fragments for GEMM2 are 8-scalar
// stride-64 gathers, prefetched before the barrier so latency hides under
// GEMM1. LDS holds only the G redistribution buffer (16x136 us = 4352 B).
__global__ __launch_bounds__(256) void gnl_kernel(
    const float* __restrict__ z,  const float* __restrict__ W1,
    const float* __restrict__ b1, const float* __restrict__ W2,
    const float* __restrict__ Wf, float* __restrict__ out)
{
    __shared__ unsigned short Gb[MT * 136];            // [16][136]

    const int tid  = threadIdx.x;
    const int lane = tid & 63, wv = tid >> 6;
    const int l15 = lane & 15, q = lane >> 4;
    const int row0 = blockIdx.x * MT;

    // ---- A-frags: coalesced fp32 z loads -> bf16 pack in regs ----
    // A[m=l15][k=q*8+j]; za0 covers k 0..31, za1 covers k 32..63.
    const float* zp = z + (size_t)(row0 + l15) * Dd + q * 8;
    bf16x8 za0 = pack8(*(const float4*)(zp + 0),  *(const float4*)(zp + 4));
    bf16x8 za1 = pack8(*(const float4*)(zp + 32), *(const float4*)(zp + 36));

    // ---- prefetch (independent of GEMM1; hides under it + barrier) ----
    const int dc = wv * 16 + l15;                      // output dim d (1 tile/wave)
    // GEMM2 B-frags: B[n=dc][k=j] = W1[j][dc], j = f*32 + q*8 + jj (stride-64 gather)
    bf16x8 wt[4];
    #pragma unroll
    for (int f = 0; f < 4; ++f) {
        const float* cp = W1 + (size_t)(f * 32 + q * 8) * Dd + dc;
        wt[f] = pack8s(cp[0], cp[64], cp[128], cp[192],
                       cp[256], cp[320], cp[384], cp[448]);
    }
    // GEMM3 B-frags: B[n=dc][k=d] = Wf[dc][d], row-major
    const float* wfp = Wf + (size_t)dc * Dd + q * 8;
    bf16x8 wf0 = pack8(*(const float4*)(wfp + 0),  *(const float4*)(wfp + 4));
    bf16x8 wf1 = pack8(*(const float4*)(wfp + 32), *(const float4*)(wfp + 36));

    // ---- GEMM1: U = Z*W1^T (K=64), fused g = W2*silu'(u+b1) -> Gb ----
    // 8 N-tiles split across 4 waves (2 each). B[n=jc][k=d] = W1[jc][d] row-major.
    #pragma unroll
    for (int nt = 0; nt < 2; ++nt) {
        const int jc = (wv * 2 + nt) * 16 + l15;       // column j of U
        const float* wp = W1 + (size_t)jc * Dd + q * 8;
        bf16x8 wb0 = pack8(*(const float4*)(wp + 0),  *(const float4*)(wp + 4));
        bf16x8 wb1 = pack8(*(const float4*)(wp + 32), *(const float4*)(wp + 36));
        f32x4 acc = {0.f, 0.f, 0.f, 0.f};
        acc = MFMA16(za0, wb0, acc);
        acc = MFMA16(za1, wb1, acc);
        const float bj = b1[jc], w2j = W2[jc];
        #pragma unroll
        for (int r = 0; r < 4; ++r) {                  // C: row=q*4+r, col=jc
            float u = acc[r] + bj;
            float s = 1.f / (1.f + __expf(-u));
            float g = w2j * (s * (1.f + u * (1.f - s)));   // W2 * silu'(u)
            Gb[(q * 4 + r) * 136 + jc] = f2bf(g);
        }
    }
    __syncthreads();

    // ---- GEMM2: GS = G*W1 (K=128) ----
    const int goff = l15 * 136 + q * 8;
    bf16x8 ga0 = *(const bf16x8*)(Gb + goff);
    bf16x8 ga1 = *(const bf16x8*)(Gb + goff + 32);
    bf16x8 ga2 = *(const bf16x8*)(Gb + goff + 64);
    bf16x8 ga3 = *(const bf16x8*)(Gb + goff + 96);

    f32x4 gs = {0.f, 0.f, 0.f, 0.f};
    gs = MFMA16(ga0, wt[0], gs);
    gs = MFMA16(ga1, wt[1], gs);
    gs = MFMA16(ga2, wt[2], gs);
    gs = MFMA16(ga3, wt[3], gs);

    // ---- GEMM3: A = Z*Wf^T (K=64) ----
    f32x4 av = {0.f, 0.f, 0.f, 0.f};
    av = MFMA16(za0, wf0, av);
    av = MFMA16(za1, wf1, av);

    // ---- epilogue: out = reversible + a^2 * gs ----
    const bool  lo  = dc < 32;                         // wave-uniform
    const int   src = lo ? dc + 32 : dc - 32;
    const float sgn = lo ? 1.f : -1.f;
    #pragma unroll
    for (int r = 0; r < 4; ++r) {
        const int rr = row0 + q * 4 + r;               // global row
        float rev = sgn * z[(size_t)rr * Dd + src];    // fp32-exact reversible
        float a = av[r];
        out[(size_t)rr * Dd + dc] = rev + a * a * gs[r];
    }
}

extern "C" void kernel_launch(void* const* d_in, const int* in_sizes, int n_in,
                              void* d_out, int out_size, void* d_ws, size_t ws_size,
                              hipStream_t stream)
{
    const float* z  = (const float*)d_in[0];
    const float* W1 = (const float*)d_in[1];
    const float* b1 = (const float*)d_in[2];
    const float* W2 = (const float*)d_in[3];
    // d_in[4] = b2: unused — gradient w.r.t. z is independent of b2
    const float* Wf = (const float*)d_in[5];
    float* out = (float*)d_out;
    (void)d_ws; (void)ws_size;

    gnl_kernel<<<Bn / MT, 256, 0, stream>>>(z, W1, b1, W2, Wf, out);
}